// Round 1
// baseline (319.423 us; speedup 1.0000x reference)
//
#include <hip/hip_runtime.h>

// Sizes (fixed by the problem)
#define N_BATCH 2
#define S_IN 256            // input spatial size (cube)
#define S_D1 128            // d1 output spatial
#define S_D2 64             // d2 output spatial
#define IN_PER_BATCH (S_IN * S_IN * S_IN)          // 16,777,216
#define D1_PER_BATCH (S_D1 * S_D1 * S_D1)          // 2,097,152
#define D2_PER_BATCH (S_D2 * S_D2 * S_D2)          // 262,144
#define X_ELEMS (N_BATCH * IN_PER_BATCH)           // 33,554,432
#define D1_ELEMS (N_BATCH * D1_PER_BATCH)          // 4,194,304
#define D2_ELEMS (N_BATCH * D2_PER_BATCH)          // 524,288

__global__ __launch_bounds__(256) void d1_kernel(
    const float* __restrict__ x, const float* __restrict__ kern,
    float* __restrict__ out)
{
    __shared__ float kw[27];
    if (threadIdx.x < 27) kw[threadIdx.x] = kern[threadIdx.x];
    __syncthreads();

    int t = blockIdx.x * blockDim.x + threadIdx.x;
    if (t >= D1_ELEMS) return;

    int w = t & (S_D1 - 1);
    int h = (t >> 7) & (S_D1 - 1);
    int d = (t >> 14) & (S_D1 - 1);
    int n = t >> 21;

    const float* xb = x + (size_t)n * IN_PER_BATCH;

    float acc = 0.0f;
#pragma unroll
    for (int a = 0; a < 3; ++a) {
        int iz = 2 * d - 1 + a;
        iz = iz < 0 ? 0 : (iz > S_IN - 1 ? S_IN - 1 : iz);
#pragma unroll
        for (int b = 0; b < 3; ++b) {
            int iy = 2 * h - 1 + b;
            iy = iy < 0 ? 0 : (iy > S_IN - 1 ? S_IN - 1 : iy);
            const float* row = xb + ((size_t)iz * S_IN + iy) * S_IN;
            const float* kr = kw + (a * 3 + b) * 3;
#pragma unroll
            for (int c = 0; c < 3; ++c) {
                int ix = 2 * w - 1 + c;
                ix = ix < 0 ? 0 : (ix > S_IN - 1 ? S_IN - 1 : ix);
                acc = fmaf(kr[c], row[ix], acc);
            }
        }
    }
    out[t] = acc;
}

__global__ __launch_bounds__(256) void d2_kernel(
    const float* __restrict__ x, const float* __restrict__ kern,
    float* __restrict__ out)
{
    __shared__ float kw[125];
    if (threadIdx.x < 125) kw[threadIdx.x] = kern[threadIdx.x];
    __syncthreads();

    int t = blockIdx.x * blockDim.x + threadIdx.x;
    if (t >= D2_ELEMS) return;

    int w = t & (S_D2 - 1);
    int h = (t >> 6) & (S_D2 - 1);
    int d = (t >> 12) & (S_D2 - 1);
    int n = t >> 18;

    const float* xb = x + (size_t)n * IN_PER_BATCH;

    float acc = 0.0f;
#pragma unroll
    for (int a = 0; a < 5; ++a) {
        int iz = 4 * d - 2 + a;
        iz = iz < 0 ? 0 : (iz > S_IN - 1 ? S_IN - 1 : iz);
#pragma unroll
        for (int b = 0; b < 5; ++b) {
            int iy = 4 * h - 2 + b;
            iy = iy < 0 ? 0 : (iy > S_IN - 1 ? S_IN - 1 : iy);
            const float* row = xb + ((size_t)iz * S_IN + iy) * S_IN;
            const float* kr = kw + (a * 5 + b) * 5;
#pragma unroll
            for (int c = 0; c < 5; ++c) {
                int ix = 4 * w - 2 + c;
                ix = ix < 0 ? 0 : (ix > S_IN - 1 ? S_IN - 1 : ix);
                acc = fmaf(kr[c], row[ix], acc);
            }
        }
    }
    out[t] = acc;
}

extern "C" void kernel_launch(void* const* d_in, const int* in_sizes, int n_in,
                              void* d_out, int out_size, void* d_ws, size_t ws_size,
                              hipStream_t stream) {
    const float* x  = (const float*)d_in[0];
    const float* k0 = (const float*)d_in[1];   // 27 floats (3x3x3)
    const float* k1 = (const float*)d_in[2];   // 125 floats (5x5x5)

    float* out0 = (float*)d_out;               // x passthrough
    float* out1 = out0 + X_ELEMS;              // d1
    float* out2 = out1 + D1_ELEMS;             // d2

    // 1) passthrough copy of x
    hipMemcpyAsync(out0, x, (size_t)X_ELEMS * sizeof(float),
                   hipMemcpyDeviceToDevice, stream);

    // 2) d1: 3x3x3 blur, stride 2
    {
        int threads = 256;
        int blocks = (D1_ELEMS + threads - 1) / threads;  // 16384
        d1_kernel<<<blocks, threads, 0, stream>>>(x, k0, out1);
    }

    // 3) d2: 5x5x5 blur, stride 4
    {
        int threads = 256;
        int blocks = (D2_ELEMS + threads - 1) / threads;  // 2048
        d2_kernel<<<blocks, threads, 0, stream>>>(x, k1, out2);
    }
}